// Round 9
// baseline (325.427 us; speedup 1.0000x reference)
//
#include <hip/hip_runtime.h>
#include <hip/hip_fp16.h>

#define BKN 4        // nodes per fine bucket (sort granularity)
#define CBN 256      // nodes per coarse bin
#define CHUNK 4096   // edges per passA block
#define MAXBIN 5120  // fixed region per coarse bin (mean 4092, sd ~64 -> 16 sigma)

typedef _Float16 half8 __attribute__((ext_vector_type(8)));
typedef _Float16 h4v __attribute__((ext_vector_type(4)));
typedef float floatx4 __attribute__((ext_vector_type(4)));

// ---------------- init: curCB[i] = i*MAXBIN (fixed-region bases) ----------------

__global__ void init_cur_kernel(int* __restrict__ p, int n, int stride) {
    int i = blockIdx.x * blockDim.x + threadIdx.x;
    if (i < n) p[i] = i * stride;
}

// ---------------- passA: multisplit edges into fixed coarse-bin regions ----------
// packed: (r<<8) | (c & 255)

__global__ __launch_bounds__(256) void passA_kernel(const int* __restrict__ ei,
                                                    int* __restrict__ curCB,
                                                    unsigned* __restrict__ binned,
                                                    int E, int NCB) {
    __shared__ int lcnt[512];
    __shared__ int sA[512], sB[512];
    __shared__ int loffx[512];
    __shared__ int gbase[512];
    __shared__ int lpos[512];
    __shared__ unsigned stage[CHUNK];
    __shared__ unsigned short sbin[CHUNK];   // bin id per staged slot -> coalesced drain
    int tid = threadIdx.x;
    int base = blockIdx.x * CHUNK;
    for (int i = tid; i < 512; i += 256) lcnt[i] = 0;
    __syncthreads();
    unsigned pk[16]; int bin[16];
    #pragma unroll
    for (int q = 0; q < 16; ++q) {
        int e = base + q * 256 + tid;
        if (e < E) {
            int r = ei[e], c = ei[E + e];
            pk[q] = ((unsigned)r << 8) | (unsigned)(c & 255);
            bin[q] = c >> 8;
            atomicAdd(&lcnt[bin[q]], 1);
        } else bin[q] = -1;
    }
    __syncthreads();
    for (int i = tid; i < 512; i += 256) sA[i] = lcnt[i];
    __syncthreads();
    int* src = sA; int* dst = sB;
    for (int o = 1; o < 512; o <<= 1) {
        for (int i = tid; i < 512; i += 256)
            dst[i] = src[i] + (i >= o ? src[i - o] : 0);
        __syncthreads();
        int* t = src; src = dst; dst = t;
    }
    for (int i = tid; i < 512; i += 256) {
        int ex = (i > 0) ? src[i - 1] : 0;
        loffx[i] = ex;
        lpos[i] = ex;
        int c = lcnt[i];
        gbase[i] = (c > 0 && i < NCB) ? atomicAdd(&curCB[i], c) : 0;
    }
    __syncthreads();
    #pragma unroll
    for (int q = 0; q < 16; ++q) {
        if (bin[q] >= 0) {
            int p = atomicAdd(&lpos[bin[q]], 1);
            stage[p] = pk[q];
            sbin[p] = (unsigned short)bin[q];
        }
    }
    __syncthreads();
    int total = min(CHUNK, E - base);
    for (int idx = tid; idx < total; idx += 256) {
        int b2 = sbin[idx];
        binned[gbase[b2] + (idx - loffx[b2])] = stage[idx];
    }
}

// ---------------- passB: 256-bin fine sort by full target; emit bktR (r only),
// per-node runs offN/endN, and dinv. One histogram replaces the old 64-bin sort
// + separate 256-bin degree count (fewer LDS atomics). bktR within a coarse bin
// is grouped by target node -> hop needs no target selects / butterflies.

__global__ __launch_bounds__(256) void passB_kernel(const unsigned* __restrict__ binned,
                                                    const int* __restrict__ curCB,
                                                    int* __restrict__ bktR,
                                                    int* __restrict__ offN,
                                                    int* __restrict__ endN,
                                                    float* __restrict__ dinv,
                                                    int N, int NCB) {
    __shared__ unsigned raw[MAXBIN];
    __shared__ int stageR[MAXBIN];
    __shared__ int fcnt[256], foff[256], fpos[256];
    __shared__ int sA[256], sB[256];
    int i = blockIdx.x;
    int tid = threadIdx.x;
    int g0 = i * MAXBIN;
    int cnt = curCB[i] - g0;
    if (cnt > MAXBIN) cnt = MAXBIN;  // safety (16-sigma unreachable)
    fcnt[tid] = 0;
    __syncthreads();
    for (int idx = tid; idx < cnt; idx += 256) {
        unsigned pk = binned[g0 + idx];
        raw[idx] = pk;
        atomicAdd(&fcnt[pk & 255], 1);
    }
    __syncthreads();
    // Hillis-Steele inclusive scan over 256 bins
    sA[tid] = fcnt[tid];
    __syncthreads();
    int* src = sA; int* dst = sB;
    for (int o = 1; o < 256; o <<= 1) {
        dst[tid] = src[tid] + (tid >= o ? src[tid - o] : 0);
        __syncthreads();
        int* t = src; src = dst; dst = t;
    }
    int excl = src[tid] - fcnt[tid];
    foff[tid] = excl;
    fpos[tid] = excl;
    __syncthreads();
    for (int idx = tid; idx < cnt; idx += 256) {
        unsigned pk = raw[idx];
        int p = atomicAdd(&fpos[pk & 255], 1);
        stageR[p] = (int)(pk >> 8);           // r only; target implicit by position
    }
    __syncthreads();
    for (int idx = tid; idx < cnt; idx += 256) bktR[g0 + idx] = stageR[idx];
    int n = i * CBN + tid;
    if (n < N) {
        offN[n] = g0 + foff[tid];
        endN[n] = g0 + foff[tid] + fcnt[tid];
        dinv[n] = rsqrtf((float)fcnt[tid] + 1.0f);
    }
}

// ---------------- weight folding (25 blocks: parallel cold-fetch) ----------------
// Single-block fold is bound by one CU's outstanding-miss capacity (~1.4 GB/s
// on cold HBM). 25 blocks spread the cold fetch across 25 CUs (round-5: WIN).
__global__ __launch_bounds__(256) void fold_kernel(
    const float* __restrict__ W1, const float* __restrict__ b1,
    const float* __restrict__ W2, const float* __restrict__ b2,
    const float* __restrict__ W3, const float* __restrict__ b3,
    const float* __restrict__ W4,
    float* __restrict__ Wf1, float* __restrict__ Wf2,
    float* __restrict__ u, float* __restrict__ v) {
    __shared__ float As[64][64];
    __shared__ float gsl[64];
    int tid = threadIdx.x;
    int f = tid & 63;
    int w = __builtin_amdgcn_readfirstlane(tid >> 6);   // wave id 0..3, SGPR
    int blk = blockIdx.x;

    float w4c[64];
    #pragma unroll
    for (int k = 0; k < 64; ++k) w4c[k] = W4[k * 64 + f];

    if (blk < 24) {
        const int half = (blk < 16) ? 0 : 64;
        #pragma unroll 2
        for (int kk = 0; kk < 16; ++kk) {
            int k = w * 16 + kk;
            float a = 0.f;
            #pragma unroll
            for (int j = 0; j < 64; ++j)
                a += W3[(half + k) * 64 + j] * w4c[j];   // uniform -> s_load
            As[k][f] = a;
        }
        __syncthreads();
        const float* Wsrc = (blk < 16) ? W1 : W2;
        float* Wdst = (blk < 16) ? Wf1 : Wf2;
        int i = ((blk < 16) ? blk : (blk - 16)) * 4 + w;
        float a = 0.f;
        #pragma unroll
        for (int k = 0; k < 64; ++k)
            a += Wsrc[i * 64 + k] * As[k][f];
        Wdst[i * 64 + f] = a;
    } else {
        float g = 0.f;
        #pragma unroll
        for (int k = 0; k < 64; ++k) g += b1[k] * W3[k * 64 + f];
        #pragma unroll
        for (int k = 0; k < 64; ++k) g += b2[k] * W3[(64 + k) * 64 + f];
        if (w == 0) gsl[f] = g;
        __syncthreads();
        if (w == 0) {
            float uu = 0.f, vv = 0.f;
            #pragma unroll
            for (int k = 0; k < 64; ++k) {
                uu += gsl[k] * w4c[k];
                vv += b3[k] * w4c[k];
            }
            u[f] = uu;
            v[f] = vv;
        }
    }
}

// ---------------- linZ via MFMA: Z = fp16( (X~ @ Wf) * dinv ), SLICED layout ----
// Z is stored as 4 column-slices: Z[sl*N*16 + n*16 + (0..15)] (sl = nt).
// Each slice is 3.2MB -> fits one XCD's 4MB L2 during hop's slice phase.
__global__ __launch_bounds__(256) void linZ_kernel(
    const float* __restrict__ lat, const float* __restrict__ cond,
    const float* __restrict__ Wf1, const float* __restrict__ Wf2,
    const float* __restrict__ dinv, _Float16* __restrict__ Z, int N) {
    __shared__ _Float16 Xs[64][104];   // pad 96->104: b128 frag reads 2-way only
    __shared__ _Float16 Wt[64][104];
    int tid = threadIdx.x;
    int n0 = blockIdx.x * 64;
    {
        const float4* lat4 = (const float4*)(lat + (size_t)n0 * 64);
        #pragma unroll
        for (int q = 0; q < 4; ++q) {
            int idx = q * 256 + tid;
            int row = idx >> 4;
            float4 v = make_float4(0.f, 0.f, 0.f, 0.f);
            if (n0 + row < N) v = lat4[idx];
            int col = (idx & 15) * 4;
            Xs[row][col + 0] = (_Float16)v.x;
            Xs[row][col + 1] = (_Float16)v.y;
            Xs[row][col + 2] = (_Float16)v.z;
            Xs[row][col + 3] = (_Float16)v.w;
        }
        const float4* cond4 = (const float4*)(cond + (size_t)n0 * 32);
        #pragma unroll
        for (int q = 0; q < 2; ++q) {
            int idx = q * 256 + tid;
            int row = idx >> 3;
            float4 v = make_float4(0.f, 0.f, 0.f, 0.f);
            if (n0 + row < N) v = cond4[idx];
            int col = 64 + (idx & 7) * 4;
            Xs[row][col + 0] = (_Float16)v.x;
            Xs[row][col + 1] = (_Float16)v.y;
            Xs[row][col + 2] = (_Float16)v.z;
            Xs[row][col + 3] = (_Float16)v.w;
        }
        for (int i = tid; i < 4096; i += 256) {
            int k = i >> 6, f = i & 63;
            Wt[f][k] = (_Float16)Wf1[i];
        }
        for (int i = tid; i < 2048; i += 256) {
            int k = i >> 6, f = i & 63;
            Wt[f][64 + k] = (_Float16)Wf2[i];
        }
    }
    __syncthreads();
    int lane = tid & 63, wave = tid >> 6;
    int quad = lane >> 4, l16 = lane & 15;
    floatx4 acc[4] = {};
    #pragma unroll
    for (int kc = 0; kc < 96; kc += 32) {
        half8 a = *(const half8*)&Xs[wave * 16 + l16][kc + quad * 8];
        #pragma unroll
        for (int nt = 0; nt < 4; ++nt) {
            half8 b = *(const half8*)&Wt[nt * 16 + l16][kc + quad * 8];
            acc[nt] = __builtin_amdgcn_mfma_f32_16x16x32_f16(a, b, acc[nt], 0, 0, 0);
        }
    }
    #pragma unroll
    for (int r = 0; r < 4; ++r) {
        int n = n0 + wave * 16 + quad * 4 + r;
        if (n < N) {
            float d = dinv[n];
            #pragma unroll
            for (int nt = 0; nt < 4; ++nt)
                Z[(size_t)nt * N * 16 + (size_t)n * 16 + l16] = (_Float16)(acc[nt][r] * d);
        }
    }
}

// ---------------- hop v3: sliced gather + per-node edge runs --------------------
// Wave = 16 nodes x 1 slice (4-lane group per node, 4 feats/lane). Edges sorted
// by target -> each group streams its node's run [offN,endN) with plain adds:
// no selects, no butterflies. Grid is slice-major (sl = bid/WPS) so resident
// blocks phase through slices; each slice = 3.2MB -> XCD-L2-resident gathers.
// Vp = fp16( dinv ⊙ true features ), sliced layout.
// FINAL=false: out16 sliced = fp16( acc*d^2 + d*wvec[f] )
// FINAL=true : out32 [N][64] = acc*d + wvec[f]
template <bool FINAL>
__global__ __launch_bounds__(256) void hop_kernel(
    const _Float16* __restrict__ Vp, const float* __restrict__ dinv,
    const int* __restrict__ offN, const int* __restrict__ endN,
    const int* __restrict__ bktR,
    const float* __restrict__ wvec, void* __restrict__ outv,
    int N, int WPS) {
    int bid = blockIdx.x;
    int sl  = bid / WPS;            // slice phase (temporal L2 blocking)
    int wg  = bid % WPS;
    int lane = threadIdx.x & 63;
    int wave = threadIdx.x >> 6;
    int nl = lane >> 2;             // node-local 0..15
    int fl = lane & 3;              // feature lane: feats sl*16 + fl*4 ..+3
    int n = wg * 64 + wave * 16 + nl;
    if (n >= N) return;
    const _Float16* Vs = Vp + (size_t)sl * N * 16;

    float a0, a1, a2, a3;
    {
        h4v h = *(const h4v*)&Vs[(size_t)n * 16 + fl * 4];   // self-loop term
        a0 = (float)h[0]; a1 = (float)h[1]; a2 = (float)h[2]; a3 = (float)h[3];
    }
    int s = offN[n], e = endN[n];
    int idx = s;
    for (; idx + 4 <= e; idx += 4) {            // 4 gathers in flight per group
        int r0 = bktR[idx + 0];
        int r1 = bktR[idx + 1];
        int r2 = bktR[idx + 2];
        int r3 = bktR[idx + 3];
        h4v h0 = *(const h4v*)&Vs[(size_t)r0 * 16 + fl * 4];
        h4v h1 = *(const h4v*)&Vs[(size_t)r1 * 16 + fl * 4];
        h4v h2 = *(const h4v*)&Vs[(size_t)r2 * 16 + fl * 4];
        h4v h3 = *(const h4v*)&Vs[(size_t)r3 * 16 + fl * 4];
        a0 += (float)h0[0] + (float)h1[0] + (float)h2[0] + (float)h3[0];
        a1 += (float)h0[1] + (float)h1[1] + (float)h2[1] + (float)h3[1];
        a2 += (float)h0[2] + (float)h1[2] + (float)h2[2] + (float)h3[2];
        a3 += (float)h0[3] + (float)h1[3] + (float)h2[3] + (float)h3[3];
    }
    for (; idx < e; ++idx) {
        int r = bktR[idx];
        h4v h = *(const h4v*)&Vs[(size_t)r * 16 + fl * 4];
        a0 += (float)h[0]; a1 += (float)h[1]; a2 += (float)h[2]; a3 += (float)h[3];
    }

    float d = dinv[n];
    float4 wv = *(const float4*)&wvec[sl * 16 + fl * 4];
    if constexpr (FINAL) {
        float4 o;
        o.x = a0 * d + wv.x;
        o.y = a1 * d + wv.y;
        o.z = a2 * d + wv.z;
        o.w = a3 * d + wv.w;
        *(float4*)&((float*)outv)[(size_t)n * 64 + sl * 16 + fl * 4] = o;
    } else {
        float dd = d * d;
        h4v o;
        o[0] = (_Float16)(a0 * dd + d * wv.x);
        o[1] = (_Float16)(a1 * dd + d * wv.y);
        o[2] = (_Float16)(a2 * dd + d * wv.z);
        o[3] = (_Float16)(a3 * dd + d * wv.w);
        *(h4v*)&((_Float16*)outv)[(size_t)sl * N * 16 + (size_t)n * 16 + fl * 4] = o;
    }
}

// ---------------- launch ----------------

static inline size_t align256(size_t x) { return (x + 255) & ~(size_t)255; }

extern "C" void kernel_launch(void* const* d_in, const int* in_sizes, int n_in,
                              void* d_out, int out_size, void* d_ws, size_t ws_size,
                              hipStream_t stream) {
    const float* latent = (const float*)d_in[0];
    const float* cond   = (const float*)d_in[1];
    const int*   ei     = (const int*)d_in[2];
    const float* W1 = (const float*)d_in[3];
    const float* b1 = (const float*)d_in[4];
    const float* W2 = (const float*)d_in[5];
    const float* b2 = (const float*)d_in[6];
    const float* W3 = (const float*)d_in[7];
    const float* b3 = (const float*)d_in[8];
    const float* W4 = (const float*)d_in[9];
    const float* b4 = (const float*)d_in[10];
    float* out = (float*)d_out;

    const int N = in_sizes[0] / 64;          // 100000
    const int E = in_sizes[2] / 2;           // 1600000
    const int NCB = (N + CBN - 1) / CBN;     // 391 coarse bins
    const int NCH = (E + CHUNK - 1) / CHUNK; // 391 chunks
    const size_t REG = (size_t)NCB * MAXBIN; // strided region total

    // workspace layout
    char* w = (char*)d_ws;
    size_t o = 0;
    int* curCB = (int*)(w + o); o = align256(o + (size_t)NCB * 4);
    int* offN  = (int*)(w + o); o = align256(o + (size_t)N * 4);
    int* endN  = (int*)(w + o); o = align256(o + (size_t)N * 4);
    float* dinv = (float*)(w + o); o = align256(o + (size_t)N * 4);
    float* Wf1 = (float*)(w + o); o = align256(o + 4096 * 4);
    float* Wf2 = (float*)(w + o); o = align256(o + 2048 * 4);
    float* uVec = (float*)(w + o); o = align256(o + 64 * 4);
    float* vVec = (float*)(w + o); o = align256(o + 64 * 4);
    unsigned* binned = (unsigned*)(w + o); o = align256(o + REG * 4);
    int* bktR        = (int*)(w + o); o = align256(o + REG * 4);
    _Float16* Z = (_Float16*)(w + o); o = align256(o + (size_t)N * 64 * 2);
    _Float16* P = (_Float16*)(w + o); o = align256(o + (size_t)N * 64 * 2);

    const int BS = 256;
    const int WPS = (N + 63) / 64;   // 1563 blocks per slice
    const int gHop = 4 * WPS;        // 4 slice phases

    // ---- build: fixed-region counting sort; emits bktR, offN/endN, dinv ----
    init_cur_kernel<<<2, BS, 0, stream>>>(curCB, NCB, MAXBIN);
    passA_kernel<<<NCH, BS, 0, stream>>>(ei, curCB, binned, E, NCB);
    passB_kernel<<<NCB, BS, 0, stream>>>(binned, curCB, bktR, offN, endN, dinv, N, NCB);

    // ---- weight fold (25 parallel blocks) + fused linear (MFMA, sliced out) ----
    fold_kernel<<<25, BS, 0, stream>>>(W1, b1, W2, b2, W3, b3, W4, Wf1, Wf2, uVec, vVec);
    linZ_kernel<<<(N + 63) / 64, BS, 0, stream>>>(latent, cond, Wf1, Wf2, dinv, Z, N);

    // ---- three hops (u, v folded into epilogues; b4 at final) ----
    hop_kernel<false><<<gHop, BS, 0, stream>>>(Z, dinv, offN, endN, bktR, uVec, (void*)P, N, WPS);
    hop_kernel<false><<<gHop, BS, 0, stream>>>(P, dinv, offN, endN, bktR, vVec, (void*)Z, N, WPS);
    hop_kernel<true ><<<gHop, BS, 0, stream>>>(Z, dinv, offN, endN, bktR, b4, (void*)out, N, WPS);
}

// Round 10
// 285.955 us; speedup vs baseline: 1.1380x; 1.1380x over previous
//
#include <hip/hip_runtime.h>
#include <hip/hip_fp16.h>

#define BKN 4        // nodes per wave-subgroup pass in hop
#define CBN 256      // nodes per coarse bin
#define CHUNK 4096   // edges per passA block
#define MAXBIN 5120  // fixed region per coarse bin (mean 4092, sd ~64 -> 16 sigma)

typedef _Float16 half8 __attribute__((ext_vector_type(8)));
typedef _Float16 h4v __attribute__((ext_vector_type(4)));
typedef float floatx4 __attribute__((ext_vector_type(4)));

// ---------------- init: curCB[i] = i*MAXBIN (fixed-region bases) ----------------

__global__ void init_cur_kernel(int* __restrict__ p, int n, int stride) {
    int i = blockIdx.x * blockDim.x + threadIdx.x;
    if (i < n) p[i] = i * stride;
}

// ---------------- passA: multisplit edges into fixed coarse-bin regions ----------
// packed: (r<<8) | (c & 255)

__global__ __launch_bounds__(256) void passA_kernel(const int* __restrict__ ei,
                                                    int* __restrict__ curCB,
                                                    unsigned* __restrict__ binned,
                                                    int E, int NCB) {
    __shared__ int lcnt[512];
    __shared__ int sA[512], sB[512];
    __shared__ int loffx[512];
    __shared__ int gbase[512];
    __shared__ int lpos[512];
    __shared__ unsigned stage[CHUNK];
    __shared__ unsigned short sbin[CHUNK];   // bin id per staged slot -> coalesced drain
    int tid = threadIdx.x;
    int base = blockIdx.x * CHUNK;
    for (int i = tid; i < 512; i += 256) lcnt[i] = 0;
    __syncthreads();
    unsigned pk[16]; int bin[16];
    #pragma unroll
    for (int q = 0; q < 16; ++q) {
        int e = base + q * 256 + tid;
        if (e < E) {
            int r = ei[e], c = ei[E + e];
            pk[q] = ((unsigned)r << 8) | (unsigned)(c & 255);
            bin[q] = c >> 8;
            atomicAdd(&lcnt[bin[q]], 1);
        } else bin[q] = -1;
    }
    __syncthreads();
    for (int i = tid; i < 512; i += 256) sA[i] = lcnt[i];
    __syncthreads();
    int* src = sA; int* dst = sB;
    for (int o = 1; o < 512; o <<= 1) {
        for (int i = tid; i < 512; i += 256)
            dst[i] = src[i] + (i >= o ? src[i - o] : 0);
        __syncthreads();
        int* t = src; src = dst; dst = t;
    }
    for (int i = tid; i < 512; i += 256) {
        int ex = (i > 0) ? src[i - 1] : 0;
        loffx[i] = ex;
        lpos[i] = ex;
        int c = lcnt[i];
        gbase[i] = (c > 0 && i < NCB) ? atomicAdd(&curCB[i], c) : 0;
    }
    __syncthreads();
    #pragma unroll
    for (int q = 0; q < 16; ++q) {
        if (bin[q] >= 0) {
            int p = atomicAdd(&lpos[bin[q]], 1);
            stage[p] = pk[q];
            sbin[p] = (unsigned short)bin[q];
        }
    }
    __syncthreads();
    int total = min(CHUNK, E - base);
    for (int idx = tid; idx < total; idx += 256) {
        int b2 = sbin[idx];
        binned[gbase[b2] + (idx - loffx[b2])] = stage[idx];
    }
}

// ---------------- passB: 256-bin fine sort by full target; emit bktR (r only),
// per-node runs offN/endN, and dinv. Edges within a run all share one target ->
// hop accumulates with plain adds (no selects). Verified correct in round 9.

__global__ __launch_bounds__(256) void passB_kernel(const unsigned* __restrict__ binned,
                                                    const int* __restrict__ curCB,
                                                    int* __restrict__ bktR,
                                                    int* __restrict__ offN,
                                                    int* __restrict__ endN,
                                                    float* __restrict__ dinv,
                                                    int N, int NCB) {
    __shared__ unsigned raw[MAXBIN];
    __shared__ int stageR[MAXBIN];
    __shared__ int fcnt[256], foff[256], fpos[256];
    __shared__ int sA[256], sB[256];
    int i = blockIdx.x;
    int tid = threadIdx.x;
    int g0 = i * MAXBIN;
    int cnt = curCB[i] - g0;
    if (cnt > MAXBIN) cnt = MAXBIN;  // safety (16-sigma unreachable)
    fcnt[tid] = 0;
    __syncthreads();
    for (int idx = tid; idx < cnt; idx += 256) {
        unsigned pk = binned[g0 + idx];
        raw[idx] = pk;
        atomicAdd(&fcnt[pk & 255], 1);
    }
    __syncthreads();
    sA[tid] = fcnt[tid];
    __syncthreads();
    int* src = sA; int* dst = sB;
    for (int o = 1; o < 256; o <<= 1) {
        dst[tid] = src[tid] + (tid >= o ? src[tid - o] : 0);
        __syncthreads();
        int* t = src; src = dst; dst = t;
    }
    int excl = src[tid] - fcnt[tid];
    foff[tid] = excl;
    fpos[tid] = excl;
    __syncthreads();
    for (int idx = tid; idx < cnt; idx += 256) {
        unsigned pk = raw[idx];
        int p = atomicAdd(&fpos[pk & 255], 1);
        stageR[p] = (int)(pk >> 8);           // r only; target implicit by position
    }
    __syncthreads();
    for (int idx = tid; idx < cnt; idx += 256) bktR[g0 + idx] = stageR[idx];
    int n = i * CBN + tid;
    if (n < N) {
        offN[n] = g0 + foff[tid];
        endN[n] = g0 + foff[tid] + fcnt[tid];
        dinv[n] = rsqrtf((float)fcnt[tid] + 1.0f);
    }
}

// ---------------- weight folding (25 blocks: parallel cold-fetch) ----------------

__global__ __launch_bounds__(256) void fold_kernel(
    const float* __restrict__ W1, const float* __restrict__ b1,
    const float* __restrict__ W2, const float* __restrict__ b2,
    const float* __restrict__ W3, const float* __restrict__ b3,
    const float* __restrict__ W4,
    float* __restrict__ Wf1, float* __restrict__ Wf2,
    float* __restrict__ u, float* __restrict__ v) {
    __shared__ float As[64][64];
    __shared__ float gsl[64];
    int tid = threadIdx.x;
    int f = tid & 63;
    int w = __builtin_amdgcn_readfirstlane(tid >> 6);
    int blk = blockIdx.x;

    float w4c[64];
    #pragma unroll
    for (int k = 0; k < 64; ++k) w4c[k] = W4[k * 64 + f];

    if (blk < 24) {
        const int half = (blk < 16) ? 0 : 64;
        #pragma unroll 2
        for (int kk = 0; kk < 16; ++kk) {
            int k = w * 16 + kk;
            float a = 0.f;
            #pragma unroll
            for (int j = 0; j < 64; ++j)
                a += W3[(half + k) * 64 + j] * w4c[j];   // uniform -> s_load
            As[k][f] = a;
        }
        __syncthreads();
        const float* Wsrc = (blk < 16) ? W1 : W2;
        float* Wdst = (blk < 16) ? Wf1 : Wf2;
        int i = ((blk < 16) ? blk : (blk - 16)) * 4 + w;
        float a = 0.f;
        #pragma unroll
        for (int k = 0; k < 64; ++k)
            a += Wsrc[i * 64 + k] * As[k][f];
        Wdst[i * 64 + f] = a;
    } else {
        float g = 0.f;
        #pragma unroll
        for (int k = 0; k < 64; ++k) g += b1[k] * W3[k * 64 + f];
        #pragma unroll
        for (int k = 0; k < 64; ++k) g += b2[k] * W3[(64 + k) * 64 + f];
        if (w == 0) gsl[f] = g;
        __syncthreads();
        if (w == 0) {
            float uu = 0.f, vv = 0.f;
            #pragma unroll
            for (int k = 0; k < 64; ++k) {
                uu += gsl[k] * w4c[k];
                vv += b3[k] * w4c[k];
            }
            u[f] = uu;
            v[f] = vv;
        }
    }
}

// ---------------- linZ via MFMA: Z[n] = fp16( (X~[n] @ Wf) * dinv[n] ), row-major

__global__ __launch_bounds__(256) void linZ_kernel(
    const float* __restrict__ lat, const float* __restrict__ cond,
    const float* __restrict__ Wf1, const float* __restrict__ Wf2,
    const float* __restrict__ dinv, _Float16* __restrict__ Z, int N) {
    __shared__ _Float16 Xs[64][104];   // pad 96->104: b128 frag reads 2-way only
    __shared__ _Float16 Wt[64][104];
    int tid = threadIdx.x;
    int n0 = blockIdx.x * 64;
    {
        const float4* lat4 = (const float4*)(lat + (size_t)n0 * 64);
        #pragma unroll
        for (int q = 0; q < 4; ++q) {
            int idx = q * 256 + tid;
            int row = idx >> 4;
            float4 v = make_float4(0.f, 0.f, 0.f, 0.f);
            if (n0 + row < N) v = lat4[idx];
            int col = (idx & 15) * 4;
            Xs[row][col + 0] = (_Float16)v.x;
            Xs[row][col + 1] = (_Float16)v.y;
            Xs[row][col + 2] = (_Float16)v.z;
            Xs[row][col + 3] = (_Float16)v.w;
        }
        const float4* cond4 = (const float4*)(cond + (size_t)n0 * 32);
        #pragma unroll
        for (int q = 0; q < 2; ++q) {
            int idx = q * 256 + tid;
            int row = idx >> 3;
            float4 v = make_float4(0.f, 0.f, 0.f, 0.f);
            if (n0 + row < N) v = cond4[idx];
            int col = 64 + (idx & 7) * 4;
            Xs[row][col + 0] = (_Float16)v.x;
            Xs[row][col + 1] = (_Float16)v.y;
            Xs[row][col + 2] = (_Float16)v.z;
            Xs[row][col + 3] = (_Float16)v.w;
        }
        for (int i = tid; i < 4096; i += 256) {
            int k = i >> 6, f = i & 63;
            Wt[f][k] = (_Float16)Wf1[i];
        }
        for (int i = tid; i < 2048; i += 256) {
            int k = i >> 6, f = i & 63;
            Wt[f][64 + k] = (_Float16)Wf2[i];
        }
    }
    __syncthreads();
    int lane = tid & 63, wave = tid >> 6;
    int quad = lane >> 4, l16 = lane & 15;
    floatx4 acc[4] = {};
    #pragma unroll
    for (int kc = 0; kc < 96; kc += 32) {
        half8 a = *(const half8*)&Xs[wave * 16 + l16][kc + quad * 8];
        #pragma unroll
        for (int nt = 0; nt < 4; ++nt) {
            half8 b = *(const half8*)&Wt[nt * 16 + l16][kc + quad * 8];
            acc[nt] = __builtin_amdgcn_mfma_f32_16x16x32_f16(a, b, acc[nt], 0, 0, 0);
        }
    }
    #pragma unroll
    for (int r = 0; r < 4; ++r) {
        int n = n0 + wave * 16 + quad * 4 + r;
        if (n < N) {
            float d = dinv[n];
            #pragma unroll
            for (int nt = 0; nt < 4; ++nt)
                Z[(size_t)n * 64 + nt * 16 + l16] = (_Float16)(acc[nt][r] * d);
        }
    }
}

// ---------------- hop v4: per-node runs, full-row gathers, select-free adds ----
// Round-9 post-mortem: slicing raised FETCH 82->148MB (32B gathers on 64B lines,
// 4x bktR re-read, slice mixing) -> HBM-bound 59us. Revert to full 128B-row
// gathers (one line per edge, consumed once). Keep per-node runs from the
// 256-bin sort: all 4 edges of an iteration share one target node, so each lane
// does 4 cvt + 4 fma per 4 edges (no target selects, ~2 VALU/edge vs 6 in r7).
// Wave = 4 nodes (one per 16-lane subgroup pass); lane (g,fq): subgroup g
// handles edge idx i0+g, feats fq*4..+3 (16 lanes x 8B = full row).
// Vp = fp16( dinv ⊙ true features ), row-major [N][64].
// FINAL=false: out16[n] = fp16( acc*d^2 + d*wvec[f] )
// FINAL=true : out32[n] = acc*d + wvec[f]
template <bool FINAL>
__global__ __launch_bounds__(256) void hop_kernel(
    const _Float16* __restrict__ Vp, const float* __restrict__ dinv,
    const int* __restrict__ offN, const int* __restrict__ endN,
    const int* __restrict__ bktR,
    const float* __restrict__ wvec, void* __restrict__ outv, int NB) {
    int lane = threadIdx.x & 63;
    int wave = threadIdx.x >> 6;
    int b = blockIdx.x * 4 + wave;
    if (b >= NB) return;
    int g  = lane >> 4;          // edge subgroup
    int fq = lane & 15;          // feature quad: feats fq*4 .. fq*4+3
    int c0 = b * BKN;

    float res[4];                // lane's final row slice for node c0+g
    #pragma unroll
    for (int t = 0; t < 4; ++t) {
        int n = c0 + t;
        int s = offN[n], e = endN[n];
        // self-loop term contributed by subgroup 0 only (summed by butterfly)
        float a0, a1, a2, a3;
        {
            h4v h = *(const h4v*)&Vp[(size_t)n * 64 + fq * 4];
            float m = (g == 0) ? 1.f : 0.f;
            a0 = m * (float)h[0]; a1 = m * (float)h[1];
            a2 = m * (float)h[2]; a3 = m * (float)h[3];
        }
        #pragma unroll 2
        for (int i0 = s; i0 < e; i0 += 4) {
            int idx = i0 + g;
            int r = bktR[min(idx, e - 1)];      // 4 dwords/wave
            h4v h = *(const h4v*)&Vp[(size_t)r * 64 + fq * 4];  // full 128B row
            float m = (idx < e) ? 1.f : 0.f;
            a0 = fmaf(m, (float)h[0], a0);
            a1 = fmaf(m, (float)h[1], a1);
            a2 = fmaf(m, (float)h[2], a2);
            a3 = fmaf(m, (float)h[3], a3);
        }
        // one butterfly per node (not per edge)
        a0 += __shfl_xor(a0, 16, 64); a0 += __shfl_xor(a0, 32, 64);
        a1 += __shfl_xor(a1, 16, 64); a1 += __shfl_xor(a1, 32, 64);
        a2 += __shfl_xor(a2, 16, 64); a2 += __shfl_xor(a2, 32, 64);
        a3 += __shfl_xor(a3, 16, 64); a3 += __shfl_xor(a3, 32, 64);
        if (g == t) { res[0] = a0; res[1] = a1; res[2] = a2; res[3] = a3; }
    }

    int n = c0 + g;
    float d = dinv[n];
    float4 wv = *(const float4*)&wvec[fq * 4];
    if constexpr (FINAL) {
        float4 o;
        o.x = res[0] * d + wv.x;
        o.y = res[1] * d + wv.y;
        o.z = res[2] * d + wv.z;
        o.w = res[3] * d + wv.w;
        *(float4*)&((float*)outv)[(size_t)n * 64 + fq * 4] = o;
    } else {
        float dd = d * d;
        h4v o;
        o[0] = (_Float16)(res[0] * dd + d * wv.x);
        o[1] = (_Float16)(res[1] * dd + d * wv.y);
        o[2] = (_Float16)(res[2] * dd + d * wv.z);
        o[3] = (_Float16)(res[3] * dd + d * wv.w);
        *(h4v*)&((_Float16*)outv)[(size_t)n * 64 + fq * 4] = o;
    }
}

// ---------------- launch ----------------

static inline size_t align256(size_t x) { return (x + 255) & ~(size_t)255; }

extern "C" void kernel_launch(void* const* d_in, const int* in_sizes, int n_in,
                              void* d_out, int out_size, void* d_ws, size_t ws_size,
                              hipStream_t stream) {
    const float* latent = (const float*)d_in[0];
    const float* cond   = (const float*)d_in[1];
    const int*   ei     = (const int*)d_in[2];
    const float* W1 = (const float*)d_in[3];
    const float* b1 = (const float*)d_in[4];
    const float* W2 = (const float*)d_in[5];
    const float* b2 = (const float*)d_in[6];
    const float* W3 = (const float*)d_in[7];
    const float* b3 = (const float*)d_in[8];
    const float* W4 = (const float*)d_in[9];
    const float* b4 = (const float*)d_in[10];
    float* out = (float*)d_out;

    const int N = in_sizes[0] / 64;          // 100000
    const int E = in_sizes[2] / 2;           // 1600000
    const int NB  = (N + BKN - 1) / BKN;     // 25000 4-node groups
    const int NCB = (N + CBN - 1) / CBN;     // 391 coarse bins
    const int NCH = (E + CHUNK - 1) / CHUNK; // 391 chunks
    const size_t REG = (size_t)NCB * MAXBIN; // strided region total

    // workspace layout
    char* w = (char*)d_ws;
    size_t o = 0;
    int* curCB = (int*)(w + o); o = align256(o + (size_t)NCB * 4);
    int* offN  = (int*)(w + o); o = align256(o + (size_t)N * 4);
    int* endN  = (int*)(w + o); o = align256(o + (size_t)N * 4);
    float* dinv = (float*)(w + o); o = align256(o + (size_t)N * 4);
    float* Wf1 = (float*)(w + o); o = align256(o + 4096 * 4);
    float* Wf2 = (float*)(w + o); o = align256(o + 2048 * 4);
    float* uVec = (float*)(w + o); o = align256(o + 64 * 4);
    float* vVec = (float*)(w + o); o = align256(o + 64 * 4);
    unsigned* binned = (unsigned*)(w + o); o = align256(o + REG * 4);
    int* bktR        = (int*)(w + o); o = align256(o + REG * 4);
    _Float16* Z = (_Float16*)(w + o); o = align256(o + (size_t)N * 64 * 2);
    _Float16* P = (_Float16*)(w + o); o = align256(o + (size_t)N * 64 * 2);

    const int BS = 256;
    int gHop = (NB + 3) / 4;   // 6250 blocks, 4 waves each

    // ---- build: fixed-region counting sort; emits bktR, offN/endN, dinv ----
    init_cur_kernel<<<2, BS, 0, stream>>>(curCB, NCB, MAXBIN);
    passA_kernel<<<NCH, BS, 0, stream>>>(ei, curCB, binned, E, NCB);
    passB_kernel<<<NCB, BS, 0, stream>>>(binned, curCB, bktR, offN, endN, dinv, N, NCB);

    // ---- weight fold (25 parallel blocks) + fused linear (MFMA) ----
    fold_kernel<<<25, BS, 0, stream>>>(W1, b1, W2, b2, W3, b3, W4, Wf1, Wf2, uVec, vVec);
    linZ_kernel<<<(N + 63) / 64, BS, 0, stream>>>(latent, cond, Wf1, Wf2, dinv, Z, N);

    // ---- three hops (u, v folded into epilogues; b4 at final) ----
    hop_kernel<false><<<gHop, BS, 0, stream>>>(Z, dinv, offN, endN, bktR, uVec, (void*)P, NB);
    hop_kernel<false><<<gHop, BS, 0, stream>>>(P, dinv, offN, endN, bktR, vVec, (void*)Z, NB);
    hop_kernel<true ><<<gHop, BS, 0, stream>>>(Z, dinv, offN, endN, bktR, b4, (void*)out, NB);
}

// Round 11
// 260.247 us; speedup vs baseline: 1.2505x; 1.0988x over previous
//
#include <hip/hip_runtime.h>
#include <hip/hip_fp16.h>

#define BKN 4        // nodes per hop wave (one 16-lane subgroup each)
#define CBN 256      // nodes per coarse bin
#define CHUNK 4096   // edges per passA block
#define MAXBIN 5120  // fixed region per coarse bin (mean 4092, sd ~64 -> 16 sigma)

typedef _Float16 half8 __attribute__((ext_vector_type(8)));
typedef _Float16 h4v __attribute__((ext_vector_type(4)));
typedef float floatx4 __attribute__((ext_vector_type(4)));

// ---------------- init: curCB[i] = i*MAXBIN (fixed-region bases) ----------------

__global__ void init_cur_kernel(int* __restrict__ p, int n, int stride) {
    int i = blockIdx.x * blockDim.x + threadIdx.x;
    if (i < n) p[i] = i * stride;
}

// ---------------- passA: multisplit edges into fixed coarse-bin regions ----------
// packed: (r<<8) | (c & 255)

__global__ __launch_bounds__(256) void passA_kernel(const int* __restrict__ ei,
                                                    int* __restrict__ curCB,
                                                    unsigned* __restrict__ binned,
                                                    int E, int NCB) {
    __shared__ int lcnt[512];
    __shared__ int sA[512], sB[512];
    __shared__ int loffx[512];
    __shared__ int gbase[512];
    __shared__ int lpos[512];
    __shared__ unsigned stage[CHUNK];
    __shared__ unsigned short sbin[CHUNK];   // bin id per staged slot -> coalesced drain
    int tid = threadIdx.x;
    int base = blockIdx.x * CHUNK;
    for (int i = tid; i < 512; i += 256) lcnt[i] = 0;
    __syncthreads();
    unsigned pk[16]; int bin[16];
    #pragma unroll
    for (int q = 0; q < 16; ++q) {
        int e = base + q * 256 + tid;
        if (e < E) {
            int r = ei[e], c = ei[E + e];
            pk[q] = ((unsigned)r << 8) | (unsigned)(c & 255);
            bin[q] = c >> 8;
            atomicAdd(&lcnt[bin[q]], 1);
        } else bin[q] = -1;
    }
    __syncthreads();
    for (int i = tid; i < 512; i += 256) sA[i] = lcnt[i];
    __syncthreads();
    int* src = sA; int* dst = sB;
    for (int o = 1; o < 512; o <<= 1) {
        for (int i = tid; i < 512; i += 256)
            dst[i] = src[i] + (i >= o ? src[i - o] : 0);
        __syncthreads();
        int* t = src; src = dst; dst = t;
    }
    for (int i = tid; i < 512; i += 256) {
        int ex = (i > 0) ? src[i - 1] : 0;
        loffx[i] = ex;
        lpos[i] = ex;
        int c = lcnt[i];
        gbase[i] = (c > 0 && i < NCB) ? atomicAdd(&curCB[i], c) : 0;
    }
    __syncthreads();
    #pragma unroll
    for (int q = 0; q < 16; ++q) {
        if (bin[q] >= 0) {
            int p = atomicAdd(&lpos[bin[q]], 1);
            stage[p] = pk[q];
            sbin[p] = (unsigned short)bin[q];
        }
    }
    __syncthreads();
    int total = min(CHUNK, E - base);
    for (int idx = tid; idx < total; idx += 256) {
        int b2 = sbin[idx];
        binned[gbase[b2] + (idx - loffx[b2])] = stage[idx];
    }
}

// ---------------- passB: 256-bin fine sort by full target; emit bktR (r only),
// per-node runs offN/endN, and dinv. Edges within a run all share one target ->
// hop accumulates with plain adds (no selects). Verified correct in rounds 9/10.

__global__ __launch_bounds__(256) void passB_kernel(const unsigned* __restrict__ binned,
                                                    const int* __restrict__ curCB,
                                                    int* __restrict__ bktR,
                                                    int* __restrict__ offN,
                                                    int* __restrict__ endN,
                                                    float* __restrict__ dinv,
                                                    int N, int NCB) {
    __shared__ unsigned raw[MAXBIN];
    __shared__ int stageR[MAXBIN];
    __shared__ int fcnt[256], foff[256], fpos[256];
    __shared__ int sA[256], sB[256];
    int i = blockIdx.x;
    int tid = threadIdx.x;
    int g0 = i * MAXBIN;
    int cnt = curCB[i] - g0;
    if (cnt > MAXBIN) cnt = MAXBIN;  // safety (16-sigma unreachable)
    fcnt[tid] = 0;
    __syncthreads();
    for (int idx = tid; idx < cnt; idx += 256) {
        unsigned pk = binned[g0 + idx];
        raw[idx] = pk;
        atomicAdd(&fcnt[pk & 255], 1);
    }
    __syncthreads();
    sA[tid] = fcnt[tid];
    __syncthreads();
    int* src = sA; int* dst = sB;
    for (int o = 1; o < 256; o <<= 1) {
        dst[tid] = src[tid] + (tid >= o ? src[tid - o] : 0);
        __syncthreads();
        int* t = src; src = dst; dst = t;
    }
    int excl = src[tid] - fcnt[tid];
    foff[tid] = excl;
    fpos[tid] = excl;
    __syncthreads();
    for (int idx = tid; idx < cnt; idx += 256) {
        unsigned pk = raw[idx];
        int p = atomicAdd(&fpos[pk & 255], 1);
        stageR[p] = (int)(pk >> 8);           // r only; target implicit by position
    }
    __syncthreads();
    for (int idx = tid; idx < cnt; idx += 256) bktR[g0 + idx] = stageR[idx];
    int n = i * CBN + tid;
    if (n < N) {
        offN[n] = g0 + foff[tid];
        endN[n] = g0 + foff[tid] + fcnt[tid];
        dinv[n] = rsqrtf((float)fcnt[tid] + 1.0f);
    }
}

// ---------------- weight folding (25 blocks: parallel cold-fetch) ----------------

__global__ __launch_bounds__(256) void fold_kernel(
    const float* __restrict__ W1, const float* __restrict__ b1,
    const float* __restrict__ W2, const float* __restrict__ b2,
    const float* __restrict__ W3, const float* __restrict__ b3,
    const float* __restrict__ W4,
    float* __restrict__ Wf1, float* __restrict__ Wf2,
    float* __restrict__ u, float* __restrict__ v) {
    __shared__ float As[64][64];
    __shared__ float gsl[64];
    int tid = threadIdx.x;
    int f = tid & 63;
    int w = __builtin_amdgcn_readfirstlane(tid >> 6);
    int blk = blockIdx.x;

    float w4c[64];
    #pragma unroll
    for (int k = 0; k < 64; ++k) w4c[k] = W4[k * 64 + f];

    if (blk < 24) {
        const int half = (blk < 16) ? 0 : 64;
        #pragma unroll 2
        for (int kk = 0; kk < 16; ++kk) {
            int k = w * 16 + kk;
            float a = 0.f;
            #pragma unroll
            for (int j = 0; j < 64; ++j)
                a += W3[(half + k) * 64 + j] * w4c[j];   // uniform -> s_load
            As[k][f] = a;
        }
        __syncthreads();
        const float* Wsrc = (blk < 16) ? W1 : W2;
        float* Wdst = (blk < 16) ? Wf1 : Wf2;
        int i = ((blk < 16) ? blk : (blk - 16)) * 4 + w;
        float a = 0.f;
        #pragma unroll
        for (int k = 0; k < 64; ++k)
            a += Wsrc[i * 64 + k] * As[k][f];
        Wdst[i * 64 + f] = a;
    } else {
        float g = 0.f;
        #pragma unroll
        for (int k = 0; k < 64; ++k) g += b1[k] * W3[k * 64 + f];
        #pragma unroll
        for (int k = 0; k < 64; ++k) g += b2[k] * W3[(64 + k) * 64 + f];
        if (w == 0) gsl[f] = g;
        __syncthreads();
        if (w == 0) {
            float uu = 0.f, vv = 0.f;
            #pragma unroll
            for (int k = 0; k < 64; ++k) {
                uu += gsl[k] * w4c[k];
                vv += b3[k] * w4c[k];
            }
            u[f] = uu;
            v[f] = vv;
        }
    }
}

// ---------------- linZ via MFMA: Z[n] = fp16( (X~[n] @ Wf) * dinv[n] ), row-major

__global__ __launch_bounds__(256) void linZ_kernel(
    const float* __restrict__ lat, const float* __restrict__ cond,
    const float* __restrict__ Wf1, const float* __restrict__ Wf2,
    const float* __restrict__ dinv, _Float16* __restrict__ Z, int N) {
    __shared__ _Float16 Xs[64][104];   // pad 96->104: b128 frag reads 2-way only
    __shared__ _Float16 Wt[64][104];
    int tid = threadIdx.x;
    int n0 = blockIdx.x * 64;
    {
        const float4* lat4 = (const float4*)(lat + (size_t)n0 * 64);
        #pragma unroll
        for (int q = 0; q < 4; ++q) {
            int idx = q * 256 + tid;
            int row = idx >> 4;
            float4 v = make_float4(0.f, 0.f, 0.f, 0.f);
            if (n0 + row < N) v = lat4[idx];
            int col = (idx & 15) * 4;
            Xs[row][col + 0] = (_Float16)v.x;
            Xs[row][col + 1] = (_Float16)v.y;
            Xs[row][col + 2] = (_Float16)v.z;
            Xs[row][col + 3] = (_Float16)v.w;
        }
        const float4* cond4 = (const float4*)(cond + (size_t)n0 * 32);
        #pragma unroll
        for (int q = 0; q < 2; ++q) {
            int idx = q * 256 + tid;
            int row = idx >> 3;
            float4 v = make_float4(0.f, 0.f, 0.f, 0.f);
            if (n0 + row < N) v = cond4[idx];
            int col = 64 + (idx & 7) * 4;
            Xs[row][col + 0] = (_Float16)v.x;
            Xs[row][col + 1] = (_Float16)v.y;
            Xs[row][col + 2] = (_Float16)v.z;
            Xs[row][col + 3] = (_Float16)v.w;
        }
        for (int i = tid; i < 4096; i += 256) {
            int k = i >> 6, f = i & 63;
            Wt[f][k] = (_Float16)Wf1[i];
        }
        for (int i = tid; i < 2048; i += 256) {
            int k = i >> 6, f = i & 63;
            Wt[f][64 + k] = (_Float16)Wf2[i];
        }
    }
    __syncthreads();
    int lane = tid & 63, wave = tid >> 6;
    int quad = lane >> 4, l16 = lane & 15;
    floatx4 acc[4] = {};
    #pragma unroll
    for (int kc = 0; kc < 96; kc += 32) {
        half8 a = *(const half8*)&Xs[wave * 16 + l16][kc + quad * 8];
        #pragma unroll
        for (int nt = 0; nt < 4; ++nt) {
            half8 b = *(const half8*)&Wt[nt * 16 + l16][kc + quad * 8];
            acc[nt] = __builtin_amdgcn_mfma_f32_16x16x32_f16(a, b, acc[nt], 0, 0, 0);
        }
    }
    #pragma unroll
    for (int r = 0; r < 4; ++r) {
        int n = n0 + wave * 16 + quad * 4 + r;
        if (n < N) {
            float d = dinv[n];
            #pragma unroll
            for (int nt = 0; nt < 4; ++nt)
                Z[(size_t)n * 64 + nt * 16 + l16] = (_Float16)(acc[nt][r] * d);
        }
    }
}

// ---------------- hop v5: concurrent per-subgroup runs, 8-deep gather pipeline --
// Round-10 post-mortem: v4's serial per-node loops left only ~2 gathers in
// flight -> latency-bound (43.5us, VALUBusy 35%, 2.6 TB/s). v5: subgroup g owns
// node c0+g's run CONCURRENTLY; lane (g,fq) accumulates feats fq*4..+3 directly.
// No butterflies, no selects, no mask-fma (run bounds are subgroup-uniform;
// inter-subgroup divergence is exec-masked, no wasted fetches). Inner loop
// unrolled 8-deep: 8 bktR broadcasts + 8 full-128B-row gathers in flight
// (4KB/wave, matching the round-6 v2 depth) with independent accumulate chains.
// Vp = fp16( dinv ⊙ true features ), row-major [N][64].
// FINAL=false: out16[n] = fp16( acc*d^2 + d*wvec[f] )
// FINAL=true : out32[n] = acc*d + wvec[f]
template <bool FINAL>
__global__ __launch_bounds__(256) void hop_kernel(
    const _Float16* __restrict__ Vp, const float* __restrict__ dinv,
    const int* __restrict__ offN, const int* __restrict__ endN,
    const int* __restrict__ bktR,
    const float* __restrict__ wvec, void* __restrict__ outv, int NB) {
    int lane = threadIdx.x & 63;
    int wave = threadIdx.x >> 6;
    int b = blockIdx.x * 4 + wave;
    if (b >= NB) return;
    int g  = lane >> 4;          // subgroup == node slot
    int fq = lane & 15;          // feature quad: feats fq*4 .. fq*4+3
    int n = b * BKN + g;

    float a0, a1, a2, a3;
    {
        h4v h = *(const h4v*)&Vp[(size_t)n * 64 + fq * 4];   // self-loop term
        a0 = (float)h[0]; a1 = (float)h[1]; a2 = (float)h[2]; a3 = (float)h[3];
    }
    int s = offN[n], e = endN[n];
    int idx = s;
    for (; idx + 8 <= e; idx += 8) {
        int r0 = bktR[idx + 0], r1 = bktR[idx + 1];
        int r2 = bktR[idx + 2], r3 = bktR[idx + 3];
        int r4 = bktR[idx + 4], r5 = bktR[idx + 5];
        int r6 = bktR[idx + 6], r7 = bktR[idx + 7];
        h4v h0 = *(const h4v*)&Vp[(size_t)r0 * 64 + fq * 4];
        h4v h1 = *(const h4v*)&Vp[(size_t)r1 * 64 + fq * 4];
        h4v h2 = *(const h4v*)&Vp[(size_t)r2 * 64 + fq * 4];
        h4v h3 = *(const h4v*)&Vp[(size_t)r3 * 64 + fq * 4];
        h4v h4_ = *(const h4v*)&Vp[(size_t)r4 * 64 + fq * 4];
        h4v h5 = *(const h4v*)&Vp[(size_t)r5 * 64 + fq * 4];
        h4v h6 = *(const h4v*)&Vp[(size_t)r6 * 64 + fq * 4];
        h4v h7 = *(const h4v*)&Vp[(size_t)r7 * 64 + fq * 4];
        a0 += ((float)h0[0] + (float)h1[0]) + ((float)h2[0] + (float)h3[0])
            + ((float)h4_[0] + (float)h5[0]) + ((float)h6[0] + (float)h7[0]);
        a1 += ((float)h0[1] + (float)h1[1]) + ((float)h2[1] + (float)h3[1])
            + ((float)h4_[1] + (float)h5[1]) + ((float)h6[1] + (float)h7[1]);
        a2 += ((float)h0[2] + (float)h1[2]) + ((float)h2[2] + (float)h3[2])
            + ((float)h4_[2] + (float)h5[2]) + ((float)h6[2] + (float)h7[2]);
        a3 += ((float)h0[3] + (float)h1[3]) + ((float)h2[3] + (float)h3[3])
            + ((float)h4_[3] + (float)h5[3]) + ((float)h6[3] + (float)h7[3]);
    }
    for (; idx + 4 <= e; idx += 4) {
        int r0 = bktR[idx + 0], r1 = bktR[idx + 1];
        int r2 = bktR[idx + 2], r3 = bktR[idx + 3];
        h4v h0 = *(const h4v*)&Vp[(size_t)r0 * 64 + fq * 4];
        h4v h1 = *(const h4v*)&Vp[(size_t)r1 * 64 + fq * 4];
        h4v h2 = *(const h4v*)&Vp[(size_t)r2 * 64 + fq * 4];
        h4v h3 = *(const h4v*)&Vp[(size_t)r3 * 64 + fq * 4];
        a0 += ((float)h0[0] + (float)h1[0]) + ((float)h2[0] + (float)h3[0]);
        a1 += ((float)h0[1] + (float)h1[1]) + ((float)h2[1] + (float)h3[1]);
        a2 += ((float)h0[2] + (float)h1[2]) + ((float)h2[2] + (float)h3[2]);
        a3 += ((float)h0[3] + (float)h1[3]) + ((float)h2[3] + (float)h3[3]);
    }
    for (; idx < e; ++idx) {
        int r = bktR[idx];
        h4v h = *(const h4v*)&Vp[(size_t)r * 64 + fq * 4];
        a0 += (float)h[0]; a1 += (float)h[1]; a2 += (float)h[2]; a3 += (float)h[3];
    }

    float d = dinv[n];
    float4 wv = *(const float4*)&wvec[fq * 4];
    if constexpr (FINAL) {
        float4 o;
        o.x = a0 * d + wv.x;
        o.y = a1 * d + wv.y;
        o.z = a2 * d + wv.z;
        o.w = a3 * d + wv.w;
        *(float4*)&((float*)outv)[(size_t)n * 64 + fq * 4] = o;
    } else {
        float dd = d * d;
        h4v o;
        o[0] = (_Float16)(a0 * dd + d * wv.x);
        o[1] = (_Float16)(a1 * dd + d * wv.y);
        o[2] = (_Float16)(a2 * dd + d * wv.z);
        o[3] = (_Float16)(a3 * dd + d * wv.w);
        *(h4v*)&((_Float16*)outv)[(size_t)n * 64 + fq * 4] = o;
    }
}

// ---------------- launch ----------------

static inline size_t align256(size_t x) { return (x + 255) & ~(size_t)255; }

extern "C" void kernel_launch(void* const* d_in, const int* in_sizes, int n_in,
                              void* d_out, int out_size, void* d_ws, size_t ws_size,
                              hipStream_t stream) {
    const float* latent = (const float*)d_in[0];
    const float* cond   = (const float*)d_in[1];
    const int*   ei     = (const int*)d_in[2];
    const float* W1 = (const float*)d_in[3];
    const float* b1 = (const float*)d_in[4];
    const float* W2 = (const float*)d_in[5];
    const float* b2 = (const float*)d_in[6];
    const float* W3 = (const float*)d_in[7];
    const float* b3 = (const float*)d_in[8];
    const float* W4 = (const float*)d_in[9];
    const float* b4 = (const float*)d_in[10];
    float* out = (float*)d_out;

    const int N = in_sizes[0] / 64;          // 100000
    const int E = in_sizes[2] / 2;           // 1600000
    const int NB  = (N + BKN - 1) / BKN;     // 25000 4-node groups
    const int NCB = (N + CBN - 1) / CBN;     // 391 coarse bins
    const int NCH = (E + CHUNK - 1) / CHUNK; // 391 chunks
    const size_t REG = (size_t)NCB * MAXBIN; // strided region total

    // workspace layout
    char* w = (char*)d_ws;
    size_t o = 0;
    int* curCB = (int*)(w + o); o = align256(o + (size_t)NCB * 4);
    int* offN  = (int*)(w + o); o = align256(o + (size_t)N * 4);
    int* endN  = (int*)(w + o); o = align256(o + (size_t)N * 4);
    float* dinv = (float*)(w + o); o = align256(o + (size_t)N * 4);
    float* Wf1 = (float*)(w + o); o = align256(o + 4096 * 4);
    float* Wf2 = (float*)(w + o); o = align256(o + 2048 * 4);
    float* uVec = (float*)(w + o); o = align256(o + 64 * 4);
    float* vVec = (float*)(w + o); o = align256(o + 64 * 4);
    unsigned* binned = (unsigned*)(w + o); o = align256(o + REG * 4);
    int* bktR        = (int*)(w + o); o = align256(o + REG * 4);
    _Float16* Z = (_Float16*)(w + o); o = align256(o + (size_t)N * 64 * 2);
    _Float16* P = (_Float16*)(w + o); o = align256(o + (size_t)N * 64 * 2);

    const int BS = 256;
    int gHop = (NB + 3) / 4;   // 6250 blocks, 4 waves each

    // ---- build: fixed-region counting sort; emits bktR, offN/endN, dinv ----
    init_cur_kernel<<<2, BS, 0, stream>>>(curCB, NCB, MAXBIN);
    passA_kernel<<<NCH, BS, 0, stream>>>(ei, curCB, binned, E, NCB);
    passB_kernel<<<NCB, BS, 0, stream>>>(binned, curCB, bktR, offN, endN, dinv, N, NCB);

    // ---- weight fold (25 parallel blocks) + fused linear (MFMA) ----
    fold_kernel<<<25, BS, 0, stream>>>(W1, b1, W2, b2, W3, b3, W4, Wf1, Wf2, uVec, vVec);
    linZ_kernel<<<(N + 63) / 64, BS, 0, stream>>>(latent, cond, Wf1, Wf2, dinv, Z, N);

    // ---- three hops (u, v folded into epilogues; b4 at final) ----
    hop_kernel<false><<<gHop, BS, 0, stream>>>(Z, dinv, offN, endN, bktR, uVec, (void*)P, NB);
    hop_kernel<false><<<gHop, BS, 0, stream>>>(P, dinv, offN, endN, bktR, vVec, (void*)Z, NB);
    hop_kernel<true ><<<gHop, BS, 0, stream>>>(Z, dinv, offN, endN, bktR, b4, (void*)out, NB);
}